// Round 2
// baseline (316.959 us; speedup 1.0000x reference)
//
#include <hip/hip_runtime.h>

#define N_NODES 50000
#define N_EDGES 800000
#define DIM 128
#define EDGE_BLOCKS ((N_EDGES + 255) / 256)
#define WT_BLOCKS 192              // 3 * 128*128 / 256
#define GEMM_BLOCKS ((N_NODES + 127) / 128)
#define SCAN_BLOCKS ((N_NODES + 255) / 256)

typedef unsigned int u32;
typedef short bf16x8 __attribute__((ext_vector_type(8)));
typedef float f32x4 __attribute__((ext_vector_type(4)));

static inline size_t alignUp(size_t x) { return (x + 255) & ~size_t(255); }

// fp32 -> bf16 round-to-nearest-even (finite values)
__device__ inline unsigned short f2bf(float f) {
    union { float f; u32 u; } v; v.f = f;
    u32 r = v.u + 0x7fffu + ((v.u >> 16) & 1u);
    return (unsigned short)(r >> 16);
}
__device__ inline float bf_lo(u32 u) { return __uint_as_float(u << 16); }
__device__ inline float bf_hi(u32 u) { return __uint_as_float(u & 0xffff0000u); }

// ---------------- fused: W->bf16 transpose (blocks [0,WT_BLOCKS)) + degree count ----------------
// Count-only: atomics into 200 KB L2-resident cnt[]; no large scattered writes here.
__global__ __launch_bounds__(256) void prep_kernel(const float* __restrict__ W1,
                                                   const float* __restrict__ W2,
                                                   const float* __restrict__ W3,
                                                   unsigned short* __restrict__ Wt,
                                                   const int* __restrict__ dst,
                                                   int* __restrict__ cnt) {
    int bid = blockIdx.x;
    if (bid < WT_BLOCKS) {
        int m = bid >> 6;                       // which matrix
        int e = (bid & 63) * 256 + threadIdx.x; // element within 128x128
        int n = e >> 7, k = e & 127;
        const float* W = (m == 0) ? W1 : (m == 1) ? W2 : W3;
        Wt[m * DIM * DIM + n * DIM + k] = f2bf(W[(size_t)k * DIM + n]);
        return;
    }
    int i = (bid - WT_BLOCKS) * 256 + threadIdx.x;
    if (i < N_EDGES) atomicAdd(&cnt[dst[i]], 1);
}

// ---------------- offsets: per-wave scan + one atomic per wave -------------------
// Node ranges may be assigned in any order (CSR row order is irrelevant), so no
// global prefix scan is needed. Also precomputes dinv = rsqrt(deg+1).
__global__ __launch_bounds__(256) void offsets_kernel(const int* __restrict__ cnt,
                                                      int* __restrict__ total,
                                                      int* __restrict__ base,
                                                      int* __restrict__ cur,
                                                      float* __restrict__ dinv) {
    int i = blockIdx.x * 256 + threadIdx.x;
    int lane = threadIdx.x & 63;
    int c = (i < N_NODES) ? cnt[i] : 0;
    int v = c;
#pragma unroll
    for (int off = 1; off < 64; off <<= 1) {
        int u = __shfl_up(v, off, 64);
        if (lane >= off) v += u;
    }
    int wsum = __shfl(v, 63, 64);
    int wbase = 0;
    if (lane == 63) wbase = atomicAdd(total, wsum);
    wbase = __shfl(wbase, 63, 64);
    if (i < N_NODES) {
        int b = wbase + v - c;   // exclusive within wave + wave base
        base[i] = b;
        cur[i]  = b;
        dinv[i] = rsqrtf((float)(c + 1));
    }
}

// ---------------- MFMA GEMM: h(bf16) = x(fp32->bf16) @ Wt^T ----------------
// Block 256 thr = 4 waves; out tile 128 rows x 128 cols; wave owns 32 rows.
// LDS tiles padded to stride 40 shorts (80 B) -> 2-way bank alias (free).
// Blocks >= GEMM_BLOCKS (layer-1 launch only) run the compact-CSR edge scatter:
// u16 indices into a 1.6 MB region -> dirty set is L2-resident, writebacks ~2 MB
// instead of the old 48 MB direct-mapped scatter.
#define LDSTRIDE 40
__global__ __launch_bounds__(256) void gemm_mfma_kernel(const float* __restrict__ x,
                                                        const unsigned short* __restrict__ Wt,
                                                        unsigned short* __restrict__ hb,
                                                        int n_rows,
                                                        const int* __restrict__ src,
                                                        const int* __restrict__ dst,
                                                        int* __restrict__ cur,
                                                        unsigned short* __restrict__ csr16) {
    if (blockIdx.x >= GEMM_BLOCKS) {
        int i = (blockIdx.x - GEMM_BLOCKS) * 256 + threadIdx.x;
        if (i < N_EDGES) {
            int d = dst[i];
            int pos = atomicAdd(&cur[d], 1);
            if (pos < N_EDGES) csr16[pos] = (unsigned short)src[i];
        }
        return;
    }
    __shared__ unsigned short As[128 * LDSTRIDE];
    __shared__ unsigned short Bs[128 * LDSTRIDE];
    const int tid = threadIdx.x;
    const int wave = tid >> 6;
    const int lane = tid & 63;
    const int quad = lane >> 4;
    const int l16 = lane & 15;
    const int row0 = blockIdx.x * 128;

    f32x4 acc[2][8];
#pragma unroll
    for (int mt = 0; mt < 2; mt++)
#pragma unroll
        for (int nt = 0; nt < 8; nt++) acc[mt][nt] = (f32x4){0.f, 0.f, 0.f, 0.f};

    for (int k0 = 0; k0 < DIM; k0 += 32) {
        // stage A: 128 rows x 32 k, fp32 -> bf16. 4 passes x 32 rows; 8 thr/row.
#pragma unroll
        for (int p = 0; p < 4; p++) {
            int r = p * 32 + (tid >> 3);
            int kq = (tid & 7) * 4;
            int gr = row0 + r;
            float4 v = make_float4(0.f, 0.f, 0.f, 0.f);
            if (gr < n_rows) v = *(const float4*)&x[(size_t)gr * DIM + k0 + kq];
            u32 lo = (u32)f2bf(v.x) | ((u32)f2bf(v.y) << 16);
            u32 hi = (u32)f2bf(v.z) | ((u32)f2bf(v.w) << 16);
            *(uint2*)&As[r * LDSTRIDE + kq] = make_uint2(lo, hi);
        }
        // stage B: Bs[n][k] = Wt[n][k0..+31]. 2 passes x 64 rows; 4 thr/row.
#pragma unroll
        for (int p = 0; p < 2; p++) {
            int nn = p * 64 + (tid >> 2);
            int kk = (tid & 3) * 8;
            *(uint4*)&Bs[nn * LDSTRIDE + kk] = *(const uint4*)&Wt[nn * DIM + k0 + kk];
        }
        __syncthreads();
        const int m0 = wave * 32;
        bf16x8 a0 = *(const bf16x8*)&As[(m0 + l16) * LDSTRIDE + quad * 8];
        bf16x8 a1 = *(const bf16x8*)&As[(m0 + 16 + l16) * LDSTRIDE + quad * 8];
#pragma unroll
        for (int nt = 0; nt < 8; nt++) {
            bf16x8 b = *(const bf16x8*)&Bs[(nt * 16 + l16) * LDSTRIDE + quad * 8];
            acc[0][nt] = __builtin_amdgcn_mfma_f32_16x16x32_bf16(a0, b, acc[0][nt], 0, 0, 0);
            acc[1][nt] = __builtin_amdgcn_mfma_f32_16x16x32_bf16(a1, b, acc[1][nt], 0, 0, 0);
        }
        __syncthreads();
    }
    // epilogue: C[row=quad*4+reg][col=lane&15] per 16x16 tile (m89-verified layout)
    const int m0 = wave * 32;
#pragma unroll
    for (int mt = 0; mt < 2; mt++) {
#pragma unroll
        for (int reg = 0; reg < 4; reg++) {
            int gr = row0 + m0 + mt * 16 + quad * 4 + reg;
            if (gr < n_rows) {
#pragma unroll
                for (int nt = 0; nt < 8; nt++)
                    hb[(size_t)gr * DIM + nt * 16 + l16] = f2bf(acc[mt][nt][reg]);
            }
        }
    }
}

// ---------------- aggregation over bf16 h: one WAVE per node ----------------
// out[i] = dinv[i]*(sum_s dinv[s]*h[s] + dinv[i]*h[i]) + b
__device__ inline void accum8(float acc[8], uint4 r, float w) {
    acc[0] += w * bf_lo(r.x); acc[1] += w * bf_hi(r.x);
    acc[2] += w * bf_lo(r.y); acc[3] += w * bf_hi(r.y);
    acc[4] += w * bf_lo(r.z); acc[5] += w * bf_hi(r.z);
    acc[6] += w * bf_lo(r.w); acc[7] += w * bf_hi(r.w);
}

__global__ __launch_bounds__(256) void agg_kernel(const uint4* __restrict__ hb,
                                                  const int* __restrict__ cnt,
                                                  const int* __restrict__ basep,
                                                  const unsigned short* __restrict__ csr16,
                                                  const float* __restrict__ dinv,
                                                  const float4* __restrict__ bias4,
                                                  float* __restrict__ out, int relu) {
    const int wave = threadIdx.x >> 6;
    const int lane = threadIdx.x & 63;
    const int node = blockIdx.x * 4 + wave;
    const int g = lane >> 4;
    const int l16 = lane & 15;

    const int deg = cnt[node];
    const float di = dinv[node];
    const int start = basep[node];

    float acc[8];
#pragma unroll
    for (int i = 0; i < 8; i++) acc[i] = 0.f;

    for (int b0 = 0; b0 < deg; b0 += 64) {
        int m = min(64, deg - b0);
        int e = 0; float w = 0.f;
        if (lane < m) {
            e = csr16[start + b0 + lane];
            w = dinv[e];
        }
        int j4 = 0;
        for (; j4 + 8 <= m; j4 += 8) {
            int j0 = j4 + g, j1 = j4 + 4 + g;
            int s0 = __shfl(e, j0, 64);  float w0 = __shfl(w, j0, 64);
            int s1 = __shfl(e, j1, 64);  float w1 = __shfl(w, j1, 64);
            uint4 r0 = hb[(size_t)s0 * 16 + l16];
            uint4 r1 = hb[(size_t)s1 * 16 + l16];
            accum8(acc, r0, w0);
            accum8(acc, r1, w1);
        }
        for (; j4 < m; j4 += 4) {
            int j = j4 + g;
            int jj = (j < m) ? j : 0;
            int s0 = __shfl(e, jj, 64);  float w0 = __shfl(w, jj, 64);
            if (j < m) {
                uint4 r0 = hb[(size_t)s0 * 16 + l16];
                accum8(acc, r0, w0);
            }
        }
    }
    if (g == 0) {   // self-loop (inner weight = dinv[node])
        uint4 r = hb[(size_t)node * 16 + l16];
        accum8(acc, r, di);
    }
#pragma unroll
    for (int i = 0; i < 8; i++) {
        acc[i] += __shfl_xor(acc[i], 16, 64);
        acc[i] += __shfl_xor(acc[i], 32, 64);
    }
    if (g == 0) {
        float4 b0 = bias4[l16 * 2], b1 = bias4[l16 * 2 + 1];
        float4 r0 = make_float4(di * acc[0] + b0.x, di * acc[1] + b0.y,
                                di * acc[2] + b0.z, di * acc[3] + b0.w);
        float4 r1 = make_float4(di * acc[4] + b1.x, di * acc[5] + b1.y,
                                di * acc[6] + b1.z, di * acc[7] + b1.w);
        if (relu) {
            r0.x = fmaxf(r0.x, 0.f); r0.y = fmaxf(r0.y, 0.f);
            r0.z = fmaxf(r0.z, 0.f); r0.w = fmaxf(r0.w, 0.f);
            r1.x = fmaxf(r1.x, 0.f); r1.y = fmaxf(r1.y, 0.f);
            r1.z = fmaxf(r1.z, 0.f); r1.w = fmaxf(r1.w, 0.f);
        }
        float4* o = (float4*)(out + (size_t)node * DIM);
        o[l16 * 2] = r0;
        o[l16 * 2 + 1] = r1;
    }
}

// ---------------- launch ----------------

extern "C" void kernel_launch(void* const* d_in, const int* in_sizes, int n_in,
                              void* d_out, int out_size, void* d_ws, size_t ws_size,
                              hipStream_t stream) {
    const float* x  = (const float*)d_in[0];
    const int* ei   = (const int*)d_in[1];
    const float* W1 = (const float*)d_in[2];
    const float* b1 = (const float*)d_in[3];
    const float* W2 = (const float*)d_in[4];
    const float* b2 = (const float*)d_in[5];
    const float* W3 = (const float*)d_in[6];
    const float* b3 = (const float*)d_in[7];
    const int* src = ei;
    const int* dst = ei + N_EDGES;
    float* out = (float*)d_out;

    char* w = (char*)d_ws;
    int* cnt   = (int*)w; w += alignUp((size_t)(N_NODES + 1) * 4);       // degree counts + total
    int* total = cnt + N_NODES;
    int* base  = (int*)w; w += alignUp((size_t)N_NODES * 4);             // CSR start offsets
    int* cur   = (int*)w; w += alignUp((size_t)N_NODES * 4);             // scatter cursors
    float* dinvb = (float*)w; w += alignUp((size_t)N_NODES * 4);         // rsqrt(deg+1)
    unsigned short* csr16 = (unsigned short*)w; w += alignUp((size_t)N_EDGES * 2); // compact u16 CSR
    unsigned short* wt = (unsigned short*)w; w += alignUp((size_t)3 * DIM * DIM * 2); // bf16 W^T x3
    unsigned short* hbuf = (unsigned short*)w; w += alignUp((size_t)N_NODES * DIM * 2); // bf16 h
    float* fbuf = (float*)w; w += alignUp((size_t)N_NODES * DIM * 4);    // fp32 agg out

    hipMemsetAsync(cnt, 0, (size_t)(N_NODES + 1) * 4, stream);

    int ablocks = N_NODES / 4;   // one wave per node

    prep_kernel<<<WT_BLOCKS + EDGE_BLOCKS, 256, 0, stream>>>(W1, W2, W3, wt, dst, cnt);
    offsets_kernel<<<SCAN_BLOCKS, 256, 0, stream>>>(cnt, total, base, cur, dinvb);

    // layer 1: edge scatter fused into the GEMM launch (independent work, overlaps MFMA)
    gemm_mfma_kernel<<<GEMM_BLOCKS + EDGE_BLOCKS, 256, 0, stream>>>(x, wt, hbuf, N_NODES,
                                                                    src, dst, cur, csr16);
    agg_kernel<<<ablocks, 256, 0, stream>>>((const uint4*)hbuf, cnt, base, csr16, dinvb,
                                            (const float4*)b1, fbuf, 1);

    gemm_mfma_kernel<<<GEMM_BLOCKS, 256, 0, stream>>>(fbuf, wt + DIM * DIM, hbuf, N_NODES,
                                                      nullptr, nullptr, nullptr, nullptr);
    agg_kernel<<<ablocks, 256, 0, stream>>>((const uint4*)hbuf, cnt, base, csr16, dinvb,
                                            (const float4*)b2, fbuf, 1);

    gemm_mfma_kernel<<<GEMM_BLOCKS, 256, 0, stream>>>(fbuf, wt + 2 * DIM * DIM, hbuf, N_NODES,
                                                      nullptr, nullptr, nullptr, nullptr);
    agg_kernel<<<ablocks, 256, 0, stream>>>((const uint4*)hbuf, cnt, base, csr16, dinvb,
                                            (const float4*)b3, out, 0);
}

// Round 3
// 265.384 us; speedup vs baseline: 1.1943x; 1.1943x over previous
//
#include <hip/hip_runtime.h>

#define N_NODES 50000
#define N_EDGES 800000
#define DIM 128
#define WT_BLOCKS 192              // 3 * 128*128 / 256
#define GEMM_BLOCKS ((N_NODES + 127) / 128)
#define NBUCKET ((N_NODES + 255) / 256)   // 196 buckets of 256 nodes (bucket = dst>>8)
#define P1_BLOCKS 200
#define P1_CHUNK 4000              // P1_BLOCKS * P1_CHUNK == N_EDGES
#define P2_BLOCKS 200
#define P2_CHUNK 4000

typedef unsigned int u32;
typedef short bf16x8 __attribute__((ext_vector_type(8)));
typedef float f32x4 __attribute__((ext_vector_type(4)));

static inline size_t alignUp(size_t x) { return (x + 255) & ~size_t(255); }

// fp32 -> bf16 round-to-nearest-even (finite values)
__device__ inline unsigned short f2bf(float f) {
    union { float f; u32 u; } v; v.f = f;
    u32 r = v.u + 0x7fffu + ((v.u >> 16) & 1u);
    return (unsigned short)(r >> 16);
}
__device__ inline float bf_lo(u32 u) { return __uint_as_float(u << 16); }
__device__ inline float bf_hi(u32 u) { return __uint_as_float(u & 0xffff0000u); }

// ---------------- prep: W->bf16 transpose (blocks [0,WT_BLOCKS)) + bucket counts ----------------
// Bucket histogram in LDS; flush with consecutive-address (hot-line) atomics only.
// NO per-edge random atomics anywhere in this pipeline (they cost ~64B fabric RMW each).
__global__ __launch_bounds__(256) void prep_kernel(const float* __restrict__ W1,
                                                   const float* __restrict__ W2,
                                                   const float* __restrict__ W3,
                                                   unsigned short* __restrict__ Wt,
                                                   const int* __restrict__ dst,
                                                   u32* __restrict__ bcnt) {
    __shared__ u32 hist[NBUCKET];
    int bid = blockIdx.x;
    if (bid < WT_BLOCKS) {
        int m = bid >> 6;                       // which matrix
        int e = (bid & 63) * 256 + threadIdx.x; // element within 128x128
        int n = e >> 7, k = e & 127;
        const float* W = (m == 0) ? W1 : (m == 1) ? W2 : W3;
        Wt[m * DIM * DIM + n * DIM + k] = f2bf(W[(size_t)k * DIM + n]);
        return;
    }
    int b = bid - WT_BLOCKS;
    for (int k = threadIdx.x; k < NBUCKET; k += 256) hist[k] = 0;
    __syncthreads();
    int e0 = b * P1_CHUNK;
    int e1 = min(e0 + P1_CHUNK, N_EDGES);
    for (int i = e0 + threadIdx.x; i < e1; i += 256)
        atomicAdd(&hist[((u32)dst[i]) >> 8], 1u);
    __syncthreads();
    for (int k = threadIdx.x; k < NBUCKET; k += 256)
        if (hist[k]) atomicAdd(&bcnt[k], hist[k]);
}

// ---------------- bscan: exclusive scan of 196 bucket sizes ----------------
__global__ __launch_bounds__(256) void bscan_kernel(const u32* __restrict__ bcnt,
                                                    u32* __restrict__ bbase,
                                                    u32* __restrict__ bcur) {
    __shared__ u32 wsum[4];
    int tid = threadIdx.x, lane = tid & 63, wv = tid >> 6;
    u32 c = (tid < NBUCKET) ? bcnt[tid] : 0;
    u32 v = c;
#pragma unroll
    for (int off = 1; off < 64; off <<= 1) {
        u32 u = __shfl_up(v, off, 64);
        if (lane >= off) v += u;
    }
    if (lane == 63) wsum[wv] = v;
    __syncthreads();
    u32 wo = 0;
    for (int w = 0; w < wv; w++) wo += wsum[w];
    u32 excl = wo + v - c;
    if (tid < NBUCKET) { bbase[tid] = excl; bcur[tid] = excl; }
}

// ---------------- part: partition edges into bucket-major epart (packed src|dst<<16) ----------
// One reservation atomic per (block,bucket) on hot lines; epart writes are block-private chunks.
__global__ __launch_bounds__(256) void part_kernel(const int* __restrict__ src,
                                                   const int* __restrict__ dst,
                                                   u32* __restrict__ bcur,
                                                   u32* __restrict__ epart) {
    __shared__ u32 ed[P2_CHUNK];
    __shared__ u32 hist[NBUCKET];
    __shared__ u32 cb[NBUCKET];
    __shared__ u32 rk[NBUCKET];
    int tid = threadIdx.x;
    for (int k = tid; k < NBUCKET; k += 256) { hist[k] = 0; rk[k] = 0; }
    __syncthreads();
    int e0 = blockIdx.x * P2_CHUNK;
    int e1 = min(e0 + P2_CHUNK, N_EDGES);
    for (int i = e0 + tid; i < e1; i += 256) {
        u32 s = (u32)src[i], d = (u32)dst[i];
        u32 v = s | (d << 16);
        ed[i - e0] = v;
        atomicAdd(&hist[d >> 8], 1u);
    }
    __syncthreads();
    for (int k = tid; k < NBUCKET; k += 256) {
        u32 c = hist[k];
        cb[k] = c ? atomicAdd(&bcur[k], c) : 0u;
    }
    __syncthreads();
    int n = e1 - e0;
    for (int k = tid; k < n; k += 256) {
        u32 v = ed[k];
        u32 bk = v >> 24;                   // (dst>>8), dst fits 16 bits
        u32 r = atomicAdd(&rk[bk], 1u);     // LDS rank
        epart[cb[bk] + r] = v;
    }
}

// ---------------- MFMA GEMM: h(bf16) = x(fp32->bf16) @ Wt^T ----------------
// Block 256 thr = 4 waves; out tile 128 rows x 128 cols; wave owns 32 rows.
// Blocks >= GEMM_BLOCKS (layer-1 launch only): bucket-CSR build. Each bucket block
// owns nodes [B*256, B*256+256) and a contiguous epart/csr16 slice -> coalesced
// block-private writes, zero global atomics. Reuses the GEMM's LDS.
#define LDSTRIDE 40
__global__ __launch_bounds__(256) void gemm_mfma_kernel(const float* __restrict__ x,
                                                        const unsigned short* __restrict__ Wt,
                                                        unsigned short* __restrict__ hb,
                                                        int n_rows,
                                                        const u32* __restrict__ bbase,
                                                        const u32* __restrict__ bcnt,
                                                        const u32* __restrict__ epart,
                                                        int* __restrict__ cnt,
                                                        int* __restrict__ base,
                                                        float* __restrict__ dinv,
                                                        unsigned short* __restrict__ csr16) {
    __shared__ unsigned short As[128 * LDSTRIDE];
    __shared__ unsigned short Bs[128 * LDSTRIDE];
    if (blockIdx.x >= GEMM_BLOCKS) {
        int B = blockIdx.x - GEMM_BLOCKS;   // bucket id
        u32* hcnt = (u32*)&As[0];           // 256 u32
        u32* pref = hcnt + 256;             // 256 u32 (local cursors)
        u32* wsum = pref + 256;             // 4 u32
        int tid = threadIdx.x, lane = tid & 63, wv = tid >> 6;
        int nb0 = B << 8;
        u32 ebeg = bbase[B];
        u32 esz  = bcnt[B];
        hcnt[tid] = 0;
        __syncthreads();
        for (u32 k = tid; k < esz; k += 256)
            atomicAdd(&hcnt[(epart[ebeg + k] >> 16) & 255u], 1u);
        __syncthreads();
        u32 c = hcnt[tid];
        u32 v = c;
#pragma unroll
        for (int off = 1; off < 64; off <<= 1) {
            u32 u = __shfl_up(v, off, 64);
            if (lane >= off) v += u;
        }
        if (lane == 63) wsum[wv] = v;
        __syncthreads();
        u32 wo = 0;
        for (int w = 0; w < wv; w++) wo += wsum[w];
        u32 excl = wo + v - c;              // exclusive prefix within bucket
        int node = nb0 + tid;
        if (node < N_NODES) {
            cnt[node]  = (int)c;
            base[node] = (int)(ebeg + excl);
            dinv[node] = rsqrtf((float)(c + 1));
        }
        pref[tid] = excl;
        __syncthreads();
        for (u32 k = tid; k < esz; k += 256) {
            u32 v2 = epart[ebeg + k];
            u32 dl = (v2 >> 16) & 255u;
            u32 r = atomicAdd(&pref[dl], 1u);   // LDS rank
            csr16[ebeg + r] = (unsigned short)(v2 & 0xffffu);
        }
        return;
    }
    const int tid = threadIdx.x;
    const int wave = tid >> 6;
    const int lane = tid & 63;
    const int quad = lane >> 4;
    const int l16 = lane & 15;
    const int row0 = blockIdx.x * 128;

    f32x4 acc[2][8];
#pragma unroll
    for (int mt = 0; mt < 2; mt++)
#pragma unroll
        for (int nt = 0; nt < 8; nt++) acc[mt][nt] = (f32x4){0.f, 0.f, 0.f, 0.f};

    for (int k0 = 0; k0 < DIM; k0 += 32) {
        // stage A: 128 rows x 32 k, fp32 -> bf16. 4 passes x 32 rows; 8 thr/row.
#pragma unroll
        for (int p = 0; p < 4; p++) {
            int r = p * 32 + (tid >> 3);
            int kq = (tid & 7) * 4;
            int gr = row0 + r;
            float4 v = make_float4(0.f, 0.f, 0.f, 0.f);
            if (gr < n_rows) v = *(const float4*)&x[(size_t)gr * DIM + k0 + kq];
            u32 lo = (u32)f2bf(v.x) | ((u32)f2bf(v.y) << 16);
            u32 hi = (u32)f2bf(v.z) | ((u32)f2bf(v.w) << 16);
            *(uint2*)&As[r * LDSTRIDE + kq] = make_uint2(lo, hi);
        }
        // stage B: Bs[n][k] = Wt[n][k0..+31]. 2 passes x 64 rows; 4 thr/row.
#pragma unroll
        for (int p = 0; p < 2; p++) {
            int nn = p * 64 + (tid >> 2);
            int kk = (tid & 3) * 8;
            *(uint4*)&Bs[nn * LDSTRIDE + kk] = *(const uint4*)&Wt[nn * DIM + k0 + kk];
        }
        __syncthreads();
        const int m0 = wave * 32;
        bf16x8 a0 = *(const bf16x8*)&As[(m0 + l16) * LDSTRIDE + quad * 8];
        bf16x8 a1 = *(const bf16x8*)&As[(m0 + 16 + l16) * LDSTRIDE + quad * 8];
#pragma unroll
        for (int nt = 0; nt < 8; nt++) {
            bf16x8 b = *(const bf16x8*)&Bs[(nt * 16 + l16) * LDSTRIDE + quad * 8];
            acc[0][nt] = __builtin_amdgcn_mfma_f32_16x16x32_bf16(a0, b, acc[0][nt], 0, 0, 0);
            acc[1][nt] = __builtin_amdgcn_mfma_f32_16x16x32_bf16(a1, b, acc[1][nt], 0, 0, 0);
        }
        __syncthreads();
    }
    // epilogue: C[row=quad*4+reg][col=lane&15] per 16x16 tile (m89-verified layout)
    const int m0 = wave * 32;
#pragma unroll
    for (int mt = 0; mt < 2; mt++) {
#pragma unroll
        for (int reg = 0; reg < 4; reg++) {
            int gr = row0 + m0 + mt * 16 + quad * 4 + reg;
            if (gr < n_rows) {
#pragma unroll
                for (int nt = 0; nt < 8; nt++)
                    hb[(size_t)gr * DIM + nt * 16 + l16] = f2bf(acc[mt][nt][reg]);
            }
        }
    }
}

// ---------------- aggregation over bf16 h: one WAVE per node ----------------
// out[i] = dinv[i]*(sum_s dinv[s]*h[s] + dinv[i]*h[i]) + b
__device__ inline void accum8(float acc[8], uint4 r, float w) {
    acc[0] += w * bf_lo(r.x); acc[1] += w * bf_hi(r.x);
    acc[2] += w * bf_lo(r.y); acc[3] += w * bf_hi(r.y);
    acc[4] += w * bf_lo(r.z); acc[5] += w * bf_hi(r.z);
    acc[6] += w * bf_lo(r.w); acc[7] += w * bf_hi(r.w);
}

__global__ __launch_bounds__(256) void agg_kernel(const uint4* __restrict__ hb,
                                                  const int* __restrict__ cnt,
                                                  const int* __restrict__ basep,
                                                  const unsigned short* __restrict__ csr16,
                                                  const float* __restrict__ dinv,
                                                  const float4* __restrict__ bias4,
                                                  float* __restrict__ out, int relu) {
    const int wave = threadIdx.x >> 6;
    const int lane = threadIdx.x & 63;
    const int node = blockIdx.x * 4 + wave;
    const int g = lane >> 4;
    const int l16 = lane & 15;

    const int deg = cnt[node];
    const float di = dinv[node];
    const int start = basep[node];

    float acc[8];
#pragma unroll
    for (int i = 0; i < 8; i++) acc[i] = 0.f;

    for (int b0 = 0; b0 < deg; b0 += 64) {
        int m = min(64, deg - b0);
        int e = 0; float w = 0.f;
        if (lane < m) {
            e = csr16[start + b0 + lane];
            w = dinv[e];
        }
        int j4 = 0;
        for (; j4 + 8 <= m; j4 += 8) {
            int j0 = j4 + g, j1 = j4 + 4 + g;
            int s0 = __shfl(e, j0, 64);  float w0 = __shfl(w, j0, 64);
            int s1 = __shfl(e, j1, 64);  float w1 = __shfl(w, j1, 64);
            uint4 r0 = hb[(size_t)s0 * 16 + l16];
            uint4 r1 = hb[(size_t)s1 * 16 + l16];
            accum8(acc, r0, w0);
            accum8(acc, r1, w1);
        }
        for (; j4 < m; j4 += 4) {
            int j = j4 + g;
            int jj = (j < m) ? j : 0;
            int s0 = __shfl(e, jj, 64);  float w0 = __shfl(w, jj, 64);
            if (j < m) {
                uint4 r0 = hb[(size_t)s0 * 16 + l16];
                accum8(acc, r0, w0);
            }
        }
    }
    if (g == 0) {   // self-loop (inner weight = dinv[node])
        uint4 r = hb[(size_t)node * 16 + l16];
        accum8(acc, r, di);
    }
#pragma unroll
    for (int i = 0; i < 8; i++) {
        acc[i] += __shfl_xor(acc[i], 16, 64);
        acc[i] += __shfl_xor(acc[i], 32, 64);
    }
    if (g == 0) {
        float4 b0 = bias4[l16 * 2], b1 = bias4[l16 * 2 + 1];
        float4 r0 = make_float4(di * acc[0] + b0.x, di * acc[1] + b0.y,
                                di * acc[2] + b0.z, di * acc[3] + b0.w);
        float4 r1 = make_float4(di * acc[4] + b1.x, di * acc[5] + b1.y,
                                di * acc[6] + b1.z, di * acc[7] + b1.w);
        if (relu) {
            r0.x = fmaxf(r0.x, 0.f); r0.y = fmaxf(r0.y, 0.f);
            r0.z = fmaxf(r0.z, 0.f); r0.w = fmaxf(r0.w, 0.f);
            r1.x = fmaxf(r1.x, 0.f); r1.y = fmaxf(r1.y, 0.f);
            r1.z = fmaxf(r1.z, 0.f); r1.w = fmaxf(r1.w, 0.f);
        }
        float4* o = (float4*)(out + (size_t)node * DIM);
        o[l16 * 2] = r0;
        o[l16 * 2 + 1] = r1;
    }
}

// ---------------- launch ----------------

extern "C" void kernel_launch(void* const* d_in, const int* in_sizes, int n_in,
                              void* d_out, int out_size, void* d_ws, size_t ws_size,
                              hipStream_t stream) {
    const float* x  = (const float*)d_in[0];
    const int* ei   = (const int*)d_in[1];
    const float* W1 = (const float*)d_in[2];
    const float* b1 = (const float*)d_in[3];
    const float* W2 = (const float*)d_in[4];
    const float* b2 = (const float*)d_in[5];
    const float* W3 = (const float*)d_in[6];
    const float* b3 = (const float*)d_in[7];
    const int* src = ei;
    const int* dst = ei + N_EDGES;
    float* out = (float*)d_out;

    char* w = (char*)d_ws;
    u32* bcnt  = (u32*)w; w += alignUp((size_t)NBUCKET * 4);
    u32* bbase = (u32*)w; w += alignUp((size_t)NBUCKET * 4);
    u32* bcur  = (u32*)w; w += alignUp((size_t)NBUCKET * 4);
    int* cnt   = (int*)w; w += alignUp((size_t)N_NODES * 4);
    int* base  = (int*)w; w += alignUp((size_t)N_NODES * 4);
    float* dinvb = (float*)w; w += alignUp((size_t)N_NODES * 4);
    u32* epart = (u32*)w; w += alignUp((size_t)N_EDGES * 4);            // bucket-major packed edges
    unsigned short* csr16 = (unsigned short*)w; w += alignUp((size_t)N_EDGES * 2);
    unsigned short* wt = (unsigned short*)w; w += alignUp((size_t)3 * DIM * DIM * 2);
    unsigned short* hbuf = (unsigned short*)w; w += alignUp((size_t)N_NODES * DIM * 2);
    float* fbuf = (float*)w; w += alignUp((size_t)N_NODES * DIM * 4);

    hipMemsetAsync(bcnt, 0, (size_t)NBUCKET * 4, stream);

    int ablocks = N_NODES / 4;   // one wave per node

    prep_kernel<<<WT_BLOCKS + P1_BLOCKS, 256, 0, stream>>>(W1, W2, W3, wt, dst, bcnt);
    bscan_kernel<<<1, 256, 0, stream>>>(bcnt, bbase, bcur);
    part_kernel<<<P2_BLOCKS, 256, 0, stream>>>(src, dst, bcur, epart);

    // layer 1: bucket-CSR build fused into the GEMM launch (independent, overlaps MFMA)
    gemm_mfma_kernel<<<GEMM_BLOCKS + NBUCKET, 256, 0, stream>>>(x, wt, hbuf, N_NODES,
                                                                bbase, bcnt, epart,
                                                                cnt, base, dinvb, csr16);
    agg_kernel<<<ablocks, 256, 0, stream>>>((const uint4*)hbuf, cnt, base, csr16, dinvb,
                                            (const float4*)b1, fbuf, 1);

    gemm_mfma_kernel<<<GEMM_BLOCKS, 256, 0, stream>>>(fbuf, wt + DIM * DIM, hbuf, N_NODES,
                                                      nullptr, nullptr, nullptr,
                                                      nullptr, nullptr, nullptr, nullptr);
    agg_kernel<<<ablocks, 256, 0, stream>>>((const uint4*)hbuf, cnt, base, csr16, dinvb,
                                            (const float4*)b2, fbuf, 1);

    gemm_mfma_kernel<<<GEMM_BLOCKS, 256, 0, stream>>>(fbuf, wt + 2 * DIM * DIM, hbuf, N_NODES,
                                                      nullptr, nullptr, nullptr,
                                                      nullptr, nullptr, nullptr, nullptr);
    agg_kernel<<<ablocks, 256, 0, stream>>>((const uint4*)hbuf, cnt, base, csr16, dinvb,
                                            (const float4*)b3, out, 0);
}

// Round 4
// 258.848 us; speedup vs baseline: 1.2245x; 1.0253x over previous
//
#include <hip/hip_runtime.h>

#define N_NODES 50000
#define N_EDGES 800000
#define DIM 128
#define WT_BLOCKS 192              // 3 * 128*128 / 256
#define GEMM_BLOCKS ((N_NODES + 127) / 128)
#define NBUCKET ((N_NODES + 255) / 256)   // 196 buckets of 256 nodes (bucket = dst>>8)
#define P1_BLOCKS 200
#define P1_CHUNK 4000              // P1_BLOCKS * P1_CHUNK == N_EDGES
#define P2_BLOCKS 200
#define P2_CHUNK 4000

typedef unsigned int u32;
typedef short bf16x8 __attribute__((ext_vector_type(8)));
typedef float f32x4 __attribute__((ext_vector_type(4)));

static inline size_t alignUp(size_t x) { return (x + 255) & ~size_t(255); }

// fp32 -> bf16 round-to-nearest-even (finite values)
__device__ inline unsigned short f2bf(float f) {
    union { float f; u32 u; } v; v.f = f;
    u32 r = v.u + 0x7fffu + ((v.u >> 16) & 1u);
    return (unsigned short)(r >> 16);
}
__device__ inline float bf_lo(u32 u) { return __uint_as_float(u << 16); }
__device__ inline float bf_hi(u32 u) { return __uint_as_float(u & 0xffff0000u); }

// ---------------- prep: W->bf16 transpose (blocks [0,WT_BLOCKS)) + bucket counts ----------------
// Bucket histogram in LDS; flush with consecutive-address (hot-line) atomics only.
// NO per-edge random global atomics anywhere in this pipeline (~64B fabric RMW each).
__global__ __launch_bounds__(256) void prep_kernel(const float* __restrict__ W1,
                                                   const float* __restrict__ W2,
                                                   const float* __restrict__ W3,
                                                   unsigned short* __restrict__ Wt,
                                                   const int* __restrict__ dst,
                                                   u32* __restrict__ bcnt) {
    __shared__ u32 hist[NBUCKET];
    int bid = blockIdx.x;
    if (bid < WT_BLOCKS) {
        int m = bid >> 6;                       // which matrix
        int e = (bid & 63) * 256 + threadIdx.x; // element within 128x128
        int n = e >> 7, k = e & 127;
        const float* W = (m == 0) ? W1 : (m == 1) ? W2 : W3;
        Wt[m * DIM * DIM + n * DIM + k] = f2bf(W[(size_t)k * DIM + n]);
        return;
    }
    int b = bid - WT_BLOCKS;
    for (int k = threadIdx.x; k < NBUCKET; k += 256) hist[k] = 0;
    __syncthreads();
    int e0 = b * P1_CHUNK;
    int e1 = min(e0 + P1_CHUNK, N_EDGES);
    for (int i = e0 + threadIdx.x; i < e1; i += 256)
        atomicAdd(&hist[((u32)dst[i]) >> 8], 1u);
    __syncthreads();
    for (int k = threadIdx.x; k < NBUCKET; k += 256)
        if (hist[k]) atomicAdd(&bcnt[k], hist[k]);
}

// ---------------- bscan: exclusive scan of 196 bucket sizes ----------------
__global__ __launch_bounds__(256) void bscan_kernel(const u32* __restrict__ bcnt,
                                                    u32* __restrict__ bbase,
                                                    u32* __restrict__ bcur) {
    __shared__ u32 wsum[4];
    int tid = threadIdx.x, lane = tid & 63, wv = tid >> 6;
    u32 c = (tid < NBUCKET) ? bcnt[tid] : 0;
    u32 v = c;
#pragma unroll
    for (int off = 1; off < 64; off <<= 1) {
        u32 u = __shfl_up(v, off, 64);
        if (lane >= off) v += u;
    }
    if (lane == 63) wsum[wv] = v;
    __syncthreads();
    u32 wo = 0;
    for (int w = 0; w < wv; w++) wo += wsum[w];
    u32 excl = wo + v - c;
    if (tid < NBUCKET) { bbase[tid] = excl; bcur[tid] = excl; }
}

// ---------------- part: partition edges into bucket-major epart (packed src|dst<<16) ----------
// One reservation atomic per (block,bucket) on hot lines; epart writes are block-private chunks.
__global__ __launch_bounds__(256) void part_kernel(const int* __restrict__ src,
                                                   const int* __restrict__ dst,
                                                   u32* __restrict__ bcur,
                                                   u32* __restrict__ epart) {
    __shared__ u32 ed[P2_CHUNK];
    __shared__ u32 hist[NBUCKET];
    __shared__ u32 cb[NBUCKET];
    __shared__ u32 rk[NBUCKET];
    int tid = threadIdx.x;
    for (int k = tid; k < NBUCKET; k += 256) { hist[k] = 0; rk[k] = 0; }
    __syncthreads();
    int e0 = blockIdx.x * P2_CHUNK;
    int e1 = min(e0 + P2_CHUNK, N_EDGES);
    for (int i = e0 + tid; i < e1; i += 256) {
        u32 s = (u32)src[i], d = (u32)dst[i];
        u32 v = s | (d << 16);
        ed[i - e0] = v;
        atomicAdd(&hist[d >> 8], 1u);
    }
    __syncthreads();
    for (int k = tid; k < NBUCKET; k += 256) {
        u32 c = hist[k];
        cb[k] = c ? atomicAdd(&bcur[k], c) : 0u;
    }
    __syncthreads();
    int n = e1 - e0;
    for (int k = tid; k < n; k += 256) {
        u32 v = ed[k];
        u32 bk = v >> 24;                   // (dst>>8), dst fits 16 bits
        u32 r = atomicAdd(&rk[bk], 1u);     // LDS rank
        epart[cb[bk] + r] = v;
    }
}

// ---------------- MFMA GEMM: h(bf16) = in @ Wt^T; in = fp32 x (xb==null) or bf16 xb ----------
// Block 256 thr = 4 waves; out tile 128 rows x 128 cols; wave owns 32 rows.
// Blocks >= GEMM_BLOCKS (layer-1 launch only): bucket-CSR build (see round-2 notes).
#define LDSTRIDE 40
__global__ __launch_bounds__(256) void gemm_mfma_kernel(const float* __restrict__ x,
                                                        const unsigned short* __restrict__ xb,
                                                        const unsigned short* __restrict__ Wt,
                                                        unsigned short* __restrict__ hb,
                                                        int n_rows,
                                                        const u32* __restrict__ bbase,
                                                        const u32* __restrict__ bcnt,
                                                        const u32* __restrict__ epart,
                                                        int* __restrict__ cnt,
                                                        int* __restrict__ base,
                                                        float* __restrict__ dinv,
                                                        unsigned short* __restrict__ csr16) {
    __shared__ unsigned short As[128 * LDSTRIDE];
    __shared__ unsigned short Bs[128 * LDSTRIDE];
    if (blockIdx.x >= GEMM_BLOCKS) {
        int B = blockIdx.x - GEMM_BLOCKS;   // bucket id
        u32* hcnt = (u32*)&As[0];           // 256 u32
        u32* pref = hcnt + 256;             // 256 u32 (local cursors)
        u32* wsum = pref + 256;             // 4 u32
        int tid = threadIdx.x, lane = tid & 63, wv = tid >> 6;
        int nb0 = B << 8;
        u32 ebeg = bbase[B];
        u32 esz  = bcnt[B];
        hcnt[tid] = 0;
        __syncthreads();
        for (u32 k = tid; k < esz; k += 256)
            atomicAdd(&hcnt[(epart[ebeg + k] >> 16) & 255u], 1u);
        __syncthreads();
        u32 c = hcnt[tid];
        u32 v = c;
#pragma unroll
        for (int off = 1; off < 64; off <<= 1) {
            u32 u = __shfl_up(v, off, 64);
            if (lane >= off) v += u;
        }
        if (lane == 63) wsum[wv] = v;
        __syncthreads();
        u32 wo = 0;
        for (int w = 0; w < wv; w++) wo += wsum[w];
        u32 excl = wo + v - c;              // exclusive prefix within bucket
        int node = nb0 + tid;
        if (node < N_NODES) {
            cnt[node]  = (int)c;
            base[node] = (int)(ebeg + excl);
            dinv[node] = rsqrtf((float)(c + 1));
        }
        pref[tid] = excl;
        __syncthreads();
        for (u32 k = tid; k < esz; k += 256) {
            u32 v2 = epart[ebeg + k];
            u32 dl = (v2 >> 16) & 255u;
            u32 r = atomicAdd(&pref[dl], 1u);   // LDS rank
            csr16[ebeg + r] = (unsigned short)(v2 & 0xffffu);
        }
        return;
    }
    const int tid = threadIdx.x;
    const int wave = tid >> 6;
    const int lane = tid & 63;
    const int quad = lane >> 4;
    const int l16 = lane & 15;
    const int row0 = blockIdx.x * 128;

    f32x4 acc[2][8];
#pragma unroll
    for (int mt = 0; mt < 2; mt++)
#pragma unroll
        for (int nt = 0; nt < 8; nt++) acc[mt][nt] = (f32x4){0.f, 0.f, 0.f, 0.f};

    for (int k0 = 0; k0 < DIM; k0 += 32) {
        if (xb) {
            // stage A from bf16 input: 128 rows x 32 k. 2 passes x 64 rows; 4 thr/row x 16B.
#pragma unroll
            for (int p = 0; p < 2; p++) {
                int r = p * 64 + (tid >> 2);
                int kk = (tid & 3) * 8;
                int gr = row0 + r;
                uint4 v = make_uint4(0u, 0u, 0u, 0u);
                if (gr < n_rows) v = *(const uint4*)&xb[(size_t)gr * DIM + k0 + kk];
                *(uint4*)&As[r * LDSTRIDE + kk] = v;
            }
        } else {
            // stage A from fp32 input: 4 passes x 32 rows; 8 thr/row, cvt to bf16.
#pragma unroll
            for (int p = 0; p < 4; p++) {
                int r = p * 32 + (tid >> 3);
                int kq = (tid & 7) * 4;
                int gr = row0 + r;
                float4 v = make_float4(0.f, 0.f, 0.f, 0.f);
                if (gr < n_rows) v = *(const float4*)&x[(size_t)gr * DIM + k0 + kq];
                u32 lo = (u32)f2bf(v.x) | ((u32)f2bf(v.y) << 16);
                u32 hi = (u32)f2bf(v.z) | ((u32)f2bf(v.w) << 16);
                *(uint2*)&As[r * LDSTRIDE + kq] = make_uint2(lo, hi);
            }
        }
        // stage B: Bs[n][k] = Wt[n][k0..+31]. 2 passes x 64 rows; 4 thr/row.
#pragma unroll
        for (int p = 0; p < 2; p++) {
            int nn = p * 64 + (tid >> 2);
            int kk = (tid & 3) * 8;
            *(uint4*)&Bs[nn * LDSTRIDE + kk] = *(const uint4*)&Wt[nn * DIM + k0 + kk];
        }
        __syncthreads();
        const int m0 = wave * 32;
        bf16x8 a0 = *(const bf16x8*)&As[(m0 + l16) * LDSTRIDE + quad * 8];
        bf16x8 a1 = *(const bf16x8*)&As[(m0 + 16 + l16) * LDSTRIDE + quad * 8];
#pragma unroll
        for (int nt = 0; nt < 8; nt++) {
            bf16x8 b = *(const bf16x8*)&Bs[(nt * 16 + l16) * LDSTRIDE + quad * 8];
            acc[0][nt] = __builtin_amdgcn_mfma_f32_16x16x32_bf16(a0, b, acc[0][nt], 0, 0, 0);
            acc[1][nt] = __builtin_amdgcn_mfma_f32_16x16x32_bf16(a1, b, acc[1][nt], 0, 0, 0);
        }
        __syncthreads();
    }
    // epilogue: C[row=quad*4+reg][col=lane&15] per 16x16 tile (m89-verified layout)
    const int m0 = wave * 32;
#pragma unroll
    for (int mt = 0; mt < 2; mt++) {
#pragma unroll
        for (int reg = 0; reg < 4; reg++) {
            int gr = row0 + m0 + mt * 16 + quad * 4 + reg;
            if (gr < n_rows) {
#pragma unroll
                for (int nt = 0; nt < 8; nt++)
                    hb[(size_t)gr * DIM + nt * 16 + l16] = f2bf(acc[mt][nt][reg]);
            }
        }
    }
}

// ---------------- aggregation over bf16 h: one WAVE per node ----------------
// out[i] = dinv[i]*(sum_s dinv[s]*h[s] + dinv[i]*h[i]) + b
// Output: bf16 (outb, layers 1-2 — identical bits to the GEMM's own f2bf of the
// fp32 value, so numerics are unchanged) or fp32 (outf, final layer).
__device__ inline void accum8(float acc[8], uint4 r, float w) {
    acc[0] += w * bf_lo(r.x); acc[1] += w * bf_hi(r.x);
    acc[2] += w * bf_lo(r.y); acc[3] += w * bf_hi(r.y);
    acc[4] += w * bf_lo(r.z); acc[5] += w * bf_hi(r.z);
    acc[6] += w * bf_lo(r.w); acc[7] += w * bf_hi(r.w);
}

__global__ __launch_bounds__(256) void agg_kernel(const uint4* __restrict__ hb,
                                                  const int* __restrict__ cnt,
                                                  const int* __restrict__ basep,
                                                  const unsigned short* __restrict__ csr16,
                                                  const float* __restrict__ dinv,
                                                  const float4* __restrict__ bias4,
                                                  unsigned short* __restrict__ outb,
                                                  float* __restrict__ outf, int relu) {
    const int wave = threadIdx.x >> 6;
    const int lane = threadIdx.x & 63;
    const int node = blockIdx.x * 4 + wave;
    const int g = lane >> 4;
    const int l16 = lane & 15;

    const int deg = cnt[node];
    const float di = dinv[node];
    const int start = basep[node];

    float acc[8];
#pragma unroll
    for (int i = 0; i < 8; i++) acc[i] = 0.f;

    for (int b0 = 0; b0 < deg; b0 += 64) {
        int m = min(64, deg - b0);
        int e = 0; float w = 0.f;
        if (lane < m) {
            e = csr16[start + b0 + lane];
            w = dinv[e];
        }
        int j4 = 0;
        // 16-edge block: 4 gathers in flight per lane group (MLP for the deg>=16 common case)
        for (; j4 + 16 <= m; j4 += 16) {
            int j0 = j4 + g, j1 = j4 + 4 + g, j2 = j4 + 8 + g, j3 = j4 + 12 + g;
            int s0 = __shfl(e, j0, 64);  float w0 = __shfl(w, j0, 64);
            int s1 = __shfl(e, j1, 64);  float w1 = __shfl(w, j1, 64);
            int s2 = __shfl(e, j2, 64);  float w2 = __shfl(w, j2, 64);
            int s3 = __shfl(e, j3, 64);  float w3 = __shfl(w, j3, 64);
            uint4 r0 = hb[(size_t)s0 * 16 + l16];
            uint4 r1 = hb[(size_t)s1 * 16 + l16];
            uint4 r2 = hb[(size_t)s2 * 16 + l16];
            uint4 r3 = hb[(size_t)s3 * 16 + l16];
            accum8(acc, r0, w0);
            accum8(acc, r1, w1);
            accum8(acc, r2, w2);
            accum8(acc, r3, w3);
        }
        for (; j4 + 8 <= m; j4 += 8) {
            int j0 = j4 + g, j1 = j4 + 4 + g;
            int s0 = __shfl(e, j0, 64);  float w0 = __shfl(w, j0, 64);
            int s1 = __shfl(e, j1, 64);  float w1 = __shfl(w, j1, 64);
            uint4 r0 = hb[(size_t)s0 * 16 + l16];
            uint4 r1 = hb[(size_t)s1 * 16 + l16];
            accum8(acc, r0, w0);
            accum8(acc, r1, w1);
        }
        for (; j4 < m; j4 += 4) {
            int j = j4 + g;
            int jj = (j < m) ? j : 0;
            int s0 = __shfl(e, jj, 64);  float w0 = __shfl(w, jj, 64);
            if (j < m) {
                uint4 r0 = hb[(size_t)s0 * 16 + l16];
                accum8(acc, r0, w0);
            }
        }
    }
    if (g == 0) {   // self-loop (inner weight = dinv[node])
        uint4 r = hb[(size_t)node * 16 + l16];
        accum8(acc, r, di);
    }
#pragma unroll
    for (int i = 0; i < 8; i++) {
        acc[i] += __shfl_xor(acc[i], 16, 64);
        acc[i] += __shfl_xor(acc[i], 32, 64);
    }
    if (g == 0) {
        float4 b0 = bias4[l16 * 2], b1 = bias4[l16 * 2 + 1];
        float res[8];
        res[0] = di * acc[0] + b0.x; res[1] = di * acc[1] + b0.y;
        res[2] = di * acc[2] + b0.z; res[3] = di * acc[3] + b0.w;
        res[4] = di * acc[4] + b1.x; res[5] = di * acc[5] + b1.y;
        res[6] = di * acc[6] + b1.z; res[7] = di * acc[7] + b1.w;
        if (relu) {
#pragma unroll
            for (int i = 0; i < 8; i++) res[i] = fmaxf(res[i], 0.f);
        }
        if (outb) {
            u32 p0 = (u32)f2bf(res[0]) | ((u32)f2bf(res[1]) << 16);
            u32 p1 = (u32)f2bf(res[2]) | ((u32)f2bf(res[3]) << 16);
            u32 p2 = (u32)f2bf(res[4]) | ((u32)f2bf(res[5]) << 16);
            u32 p3 = (u32)f2bf(res[6]) | ((u32)f2bf(res[7]) << 16);
            ((uint4*)outb)[(size_t)node * 16 + l16] = make_uint4(p0, p1, p2, p3);
        } else {
            float4* o = (float4*)(outf + (size_t)node * DIM);
            o[l16 * 2]     = make_float4(res[0], res[1], res[2], res[3]);
            o[l16 * 2 + 1] = make_float4(res[4], res[5], res[6], res[7]);
        }
    }
}

// ---------------- launch ----------------

extern "C" void kernel_launch(void* const* d_in, const int* in_sizes, int n_in,
                              void* d_out, int out_size, void* d_ws, size_t ws_size,
                              hipStream_t stream) {
    const float* x  = (const float*)d_in[0];
    const int* ei   = (const int*)d_in[1];
    const float* W1 = (const float*)d_in[2];
    const float* b1 = (const float*)d_in[3];
    const float* W2 = (const float*)d_in[4];
    const float* b2 = (const float*)d_in[5];
    const float* W3 = (const float*)d_in[6];
    const float* b3 = (const float*)d_in[7];
    const int* src = ei;
    const int* dst = ei + N_EDGES;
    float* out = (float*)d_out;

    char* w = (char*)d_ws;
    u32* bcnt  = (u32*)w; w += alignUp((size_t)NBUCKET * 4);
    u32* bbase = (u32*)w; w += alignUp((size_t)NBUCKET * 4);
    u32* bcur  = (u32*)w; w += alignUp((size_t)NBUCKET * 4);
    int* cnt   = (int*)w; w += alignUp((size_t)N_NODES * 4);
    int* base  = (int*)w; w += alignUp((size_t)N_NODES * 4);
    float* dinvb = (float*)w; w += alignUp((size_t)N_NODES * 4);
    u32* epart = (u32*)w; w += alignUp((size_t)N_EDGES * 4);            // bucket-major packed edges
    unsigned short* csr16 = (unsigned short*)w; w += alignUp((size_t)N_EDGES * 2);
    unsigned short* wt = (unsigned short*)w; w += alignUp((size_t)3 * DIM * DIM * 2);
    unsigned short* hbuf = (unsigned short*)w; w += alignUp((size_t)N_NODES * DIM * 2); // gemm out
    unsigned short* abuf = (unsigned short*)w; w += alignUp((size_t)N_NODES * DIM * 2); // agg out (bf16)

    hipMemsetAsync(bcnt, 0, (size_t)NBUCKET * 4, stream);

    int ablocks = N_NODES / 4;   // one wave per node

    prep_kernel<<<WT_BLOCKS + P1_BLOCKS, 256, 0, stream>>>(W1, W2, W3, wt, dst, bcnt);
    bscan_kernel<<<1, 256, 0, stream>>>(bcnt, bbase, bcur);
    part_kernel<<<P2_BLOCKS, 256, 0, stream>>>(src, dst, bcur, epart);

    // layer 1: bucket-CSR build fused into the GEMM launch (independent, overlaps MFMA)
    gemm_mfma_kernel<<<GEMM_BLOCKS + NBUCKET, 256, 0, stream>>>(x, nullptr, wt, hbuf, N_NODES,
                                                                bbase, bcnt, epart,
                                                                cnt, base, dinvb, csr16);
    agg_kernel<<<ablocks, 256, 0, stream>>>((const uint4*)hbuf, cnt, base, csr16, dinvb,
                                            (const float4*)b1, abuf, nullptr, 1);

    gemm_mfma_kernel<<<GEMM_BLOCKS, 256, 0, stream>>>(nullptr, abuf, wt + DIM * DIM, hbuf,
                                                      N_NODES, nullptr, nullptr, nullptr,
                                                      nullptr, nullptr, nullptr, nullptr);
    agg_kernel<<<ablocks, 256, 0, stream>>>((const uint4*)hbuf, cnt, base, csr16, dinvb,
                                            (const float4*)b2, abuf, nullptr, 1);

    gemm_mfma_kernel<<<GEMM_BLOCKS, 256, 0, stream>>>(nullptr, abuf, wt + 2 * DIM * DIM, hbuf,
                                                      N_NODES, nullptr, nullptr, nullptr,
                                                      nullptr, nullptr, nullptr, nullptr);
    agg_kernel<<<ablocks, 256, 0, stream>>>((const uint4*)hbuf, cnt, base, csr16, dinvb,
                                            (const float4*)b3, nullptr, out, 0);
}